// Round 3
// baseline (1126.115 us; speedup 1.0000x reference)
//
#include <hip/hip_runtime.h>

typedef unsigned short u16;
typedef unsigned int u32;
typedef __attribute__((ext_vector_type(4))) float f32x4;
typedef __attribute__((ext_vector_type(8))) short short8;
typedef __attribute__((ext_vector_type(4))) u16 u16x4;
typedef __attribute__((ext_vector_type(8))) u16 u16x8;

#define N_TOK 16384
#define C_DIM 768
#define I_DIM 1536
#define N_EXP 16
#define TM 256          // row-tile (padding granularity)
#define BK 64
#define NT1 12          // C_DIM/64 K-tiles in gemm1
#define NT2 24          // I_DIM/64 K-tiles in gemm2
#define MAXT 208        // worst-case tiles: <=144 routed + 64 shared
#define PASS_T 104      // tiles per pass (two passes)

// ctrl region int offsets (first 1MB of ws)
#define CI_COUNTS 0
#define CI_STARTS 32
#define CI_NTILES 64
#define CI_TILE_E 128        // [208]
#define CI_ESLOT 2048        // [N][2] packed (e<<24)|slot
#define CI_TOKW 36864        // [N][2] float weights
#define CI_PERM 102400       // [53248] padded row -> token (-1 = padding)
#define CI_RW 155648         // [53248] float per-row combine weight

// ws layout (bytes)
#define XB_OFF  1048576u             // bf16 x: 16384*768*2 = 25,165,824
#define WGU_OFF 26214400u            // bf16 [17][2I][C] g/u 16-interleaved, PLAIN: 80,216,064
#define WDP_OFF 106430464u           // bf16 [17][C][I] PLAIN:    40,108,032
#define ACT_OFF 146538496u           // bf16 act half: 26624*1536*2 = 81,788,928

// raw barriers + counted vmem waits (never drain vmcnt to 0 in steady state)
#define BAR() asm volatile("s_barrier" ::: "memory")
#define WAITVM(N) asm volatile("s_waitcnt vmcnt(" #N ")" ::: "memory")

__device__ __forceinline__ u16 f2bf(float f) {
  u32 x = __float_as_uint(f);
  return (u16)((x + 0x7FFFu + ((x >> 16) & 1u)) >> 16);  // RNE
}
__device__ __forceinline__ float bf2f(u16 h) {
  return __uint_as_float(((u32)h) << 16);
}
__device__ __forceinline__ void dma16(const void* g, void* l) {
  __builtin_amdgcn_global_load_lds(
      (const __attribute__((address_space(1))) unsigned int*)g,
      (__attribute__((address_space(3))) unsigned int*)l, 16, 0, 0);
}

// ---------------- weight convert: fp32 [K][N] -> bf16 [N][K] PLAIN rows.
// wgu: per expert a single [2I][C] matrix whose rows interleave g/u at 16-col
// granularity: combined row ng -> block b=ng>>5, gu=(ng>>4)&1, src col b*16+(ng&15).
__global__ void convert_kernel(const float* __restrict__ wg, const float* __restrict__ wu,
                               const float* __restrict__ wd, const float* __restrict__ swg,
                               const float* __restrict__ swu, const float* __restrict__ swd,
                               u16* __restrict__ wgu, u16* __restrict__ wdp) {
  int bid = blockIdx.x;
  int tid = threadIdx.x, lane = tid & 63, wv = tid >> 6;
  int lsub = lane >> 3, lchk = lane & 7;
  if (bid < 17 * 96) {                     // combined g/u part: 17 experts x 3072 rows
    int e = bid / 96, nb = bid % 96;
    int ng = nb * 32 + wv * 8 + lsub;      // combined dst row 0..3071
    int gu = (ng >> 4) & 1;
    int scol = ((ng >> 5) << 4) | (ng & 15);
    const float* src = (e < N_EXP) ? ((gu ? wu : wg) + (size_t)e * C_DIM * I_DIM)
                                   : (gu ? swu : swg);
    u16* drow = wgu + ((size_t)e * (2 * I_DIM) + ng) * C_DIM;
    const float* s0 = src + scol;
    for (int k0 = 0; k0 < C_DIM; k0 += 64) {
      u16x8 o;
#pragma unroll
      for (int j = 0; j < 8; j++) o[j] = f2bf(s0[(size_t)(k0 + lchk * 8 + j) * I_DIM]);
      *(u16x8*)&drow[k0 + lchk * 8] = o;
    }
  } else {                                 // wd part: [I][C] -> [C][I]
    int b2 = bid - 17 * 96;
    int e = b2 / 24, nb = b2 % 24;
    const float* src = (e < N_EXP) ? (wd + (size_t)e * I_DIM * C_DIM) : swd;
    u16* dst = wdp + (size_t)e * (I_DIM * C_DIM);
    int ng = nb * 32 + wv * 8 + lsub;
    const float* s0 = src + ng;
    u16* drow = dst + (size_t)ng * I_DIM;
    for (int k0 = 0; k0 < I_DIM; k0 += 64) {
      u16x8 o;
#pragma unroll
      for (int j = 0; j < 8; j++) o[j] = f2bf(s0[(size_t)(k0 + lchk * 8 + j) * C_DIM]);
      *(u16x8*)&drow[k0 + lchk * 8] = o;
    }
  }
}

// ---------------- router: fp32 logits, top-2, weights, counts; also casts x->bf16
__global__ void router_kernel(const float* __restrict__ x, const float* __restrict__ wgate,
                              const float* __restrict__ ebias, int* __restrict__ ctrl,
                              u16* __restrict__ xb) {
  __shared__ float xs[16 * 772];
  __shared__ float wgsT[16 * 772];      // transposed [e][c]
  __shared__ float lg[16 * 16];
  int tid = threadIdx.x;
  int tok0 = blockIdx.x * 16;
  const float4* xsrc = (const float4*)(x + (size_t)tok0 * C_DIM);
  const float4* wsrc = (const float4*)wgate;
#pragma unroll
  for (int j = 0; j < 12; j++) {
    int q = tid + j * 256;              // float4 unit, 0..3071
    float4 v = xsrc[q];
    int tk = q / 192;
    int c4 = q - tk * 192;
    *(float4*)&xs[tk * 772 + c4 * 4] = v;
    u16x4 o; o.x = f2bf(v.x); o.y = f2bf(v.y); o.z = f2bf(v.z); o.w = f2bf(v.w);
    *(u16x4*)(xb + (size_t)tok0 * C_DIM + (size_t)q * 4) = o;   // fused x->bf16 cast
    float4 w = wsrc[q];
    int c = q >> 2, e0 = (q & 3) * 4;
    wgsT[(e0 + 0) * 772 + c] = w.x;
    wgsT[(e0 + 1) * 772 + c] = w.y;
    wgsT[(e0 + 2) * 772 + c] = w.z;
    wgsT[(e0 + 3) * 772 + c] = w.w;
  }
  __syncthreads();
  int tk = tid >> 4, e = tid & 15;
  float acc = ebias[e];
  const float4* xr = (const float4*)&xs[tk * 772];
  const float4* wr = (const float4*)&wgsT[e * 772];
#pragma unroll 4
  for (int c4 = 0; c4 < 192; c4++) {
    float4 xv = xr[c4], wv = wr[c4];
    acc = fmaf(xv.x, wv.x, fmaf(xv.y, wv.y, fmaf(xv.z, wv.z, fmaf(xv.w, wv.w, acc))));
  }
  lg[tk * 16 + e] = acc;
  __syncthreads();
  if (tid < 16) {
    int n = tok0 + tid;
    float l0 = -1e30f, l1 = -1e30f; int i0 = 0, i1 = 0;
#pragma unroll
    for (int j = 0; j < 16; j++) {
      float l = lg[tid * 16 + j];
      if (l > l0) { l1 = l0; i1 = i0; l0 = l; i0 = j; }
      else if (l > l1) { l1 = l; i1 = j; }
    }
    float e1 = __expf(l1 - l0);
    float inv = 1.f / (1.f + e1);
    int s0 = atomicAdd(&ctrl[CI_COUNTS + i0], 1);
    int s1 = atomicAdd(&ctrl[CI_COUNTS + i1], 1);
    ctrl[CI_ESLOT + 2 * n]     = (i0 << 24) | s0;
    ctrl[CI_ESLOT + 2 * n + 1] = (i1 << 24) | s1;
    float* tw = (float*)(ctrl + CI_TOKW);
    tw[2 * n] = inv; tw[2 * n + 1] = e1 * inv;
  }
}

// ---------------- segment starts (padded to 256) + tile->expert map; shared = expert 16
__global__ void tiles_kernel(int* __restrict__ ctrl) {
  if (threadIdx.x != 0) return;
  int cnt[17];
#pragma unroll
  for (int e = 0; e < 16; e++) cnt[e] = ctrl[CI_COUNTS + e];
  cnt[16] = N_TOK;
  ctrl[CI_COUNTS + 16] = N_TOK;
  int cur = 0, T = 0;
  for (int e = 0; e <= 16; e++) {
    ctrl[CI_STARTS + e] = cur;
    int nt = (cnt[e] + TM - 1) >> 8;
    for (int i = 0; i < nt; i++) ctrl[CI_TILE_E + T++] = e;
    cur += nt << 8;
  }
  ctrl[CI_NTILES] = T;
}

// ---------------- scatter: fill perm[row]->token and per-row combine weight
__global__ void scatter_kernel(int* __restrict__ ctrl) {
  int n = blockIdx.x * 256 + threadIdx.x;
  const float* tw = (const float*)(ctrl + CI_TOKW);
  float* rw = (float*)(ctrl + CI_RW);
#pragma unroll
  for (int k = 0; k < 2; k++) {
    int es = ctrl[CI_ESLOT + 2 * n + k];
    int e = es >> 24;
    int slot = es & 0xFFFFFF;
    int row = ctrl[CI_STARTS + e] + slot;
    ctrl[CI_PERM + row] = n;
    rw[row] = tw[2 * n + k];
  }
  int srow = ctrl[CI_STARTS + 16] + n;     // shared expert row
  ctrl[CI_PERM + srow] = n;
  rw[srow] = 1.0f;
}

// ---------------- GEMM1: 256x256 combined tile, 8 waves, 4-phase fine pipeline.
// LDS: [2 dbuf][256 rows][64 k] per matrix, 128B rows, 8-chunk XOR (conflict-free,
// proven round-0 pattern; swizzle via per-lane SOURCE chunk + XOR'd read offset).
// Stage chunks = 64 rows (1 dma16/thread). Phases (kh,g); epoch-safe ring:
//  p1(kh0,g0): rd; st A1,B0(kt+1->!s);            BAR; 16 MFMA; BAR
//  p2(kh0,g1): rd; st A3,B1(kt+1->!s);            BAR; 16 MFMA; BAR
//  p3(kh1,g0): rd; st B2,B3(kt+1->!s);            BAR; 16 MFMA; BAR
//  p4(kh1,g1): rd; st A0,A2(kt+2->s, freed @p3);  WAITVM(2) [retires kt+1]; BAR; MFMA; BAR
__global__ __launch_bounds__(512, 2)
void gemm1_kernel(const u16* __restrict__ xb, const u16* __restrict__ wgu,
                  u16* __restrict__ act, const int* __restrict__ ctrl, int tile0) {
  __shared__ u16 As[2][256 * 64];
  __shared__ u16 Bs[2][256 * 64];
  int tt = tile0 + blockIdx.x;
  if (tt >= ctrl[CI_NTILES]) return;
  int e = ctrl[CI_TILE_E + tt];
  int row0 = tt << 8;                      // global padded row base
  int row0l = blockIdx.x << 8;             // pass-local row base (act index)
  int col0c = blockIdx.y << 8;             // combined col base
  int seg = ctrl[CI_STARTS + e];
  bool sh = (e == N_EXP);
  const u16* W = wgu + (size_t)e * (2 * I_DIM * C_DIM);
  int rlim = sh ? 0x7fffffff : (seg + ctrl[CI_COUNTS + e]);
  const int* perm = ctrl + CI_PERM;
  int tid = threadIdx.x, lane = tid & 63, wv = tid >> 6;
  int lsub = lane >> 3, lchk = lane & 7;
  int co = (lchk ^ lsub) * 8;              // per-lane swizzled source chunk (elems)
  const u16 *aS[4], *bS[4];
#pragma unroll
  for (int h = 0; h < 4; h++) {            // 64-row chunk h: rows h*64 + wv*8 + lsub
    int r = row0 + h * 64 + wv * 8 + lsub;
    int tok = sh ? (r - seg) : ((r < rlim) ? perm[r] : 0);
    aS[h] = xb + (size_t)tok * C_DIM + co;
    bS[h] = W + (size_t)(col0c + h * 64 + wv * 8 + lsub) * C_DIM + co;
  }
  int dbase = wv * 512;                    // (wv*8 rows)*64 u16; HW adds lane*16B

  auto stA = [&](int kt, int h) { dma16(aS[h] + kt * BK, &As[kt & 1][h * 4096 + dbase]); };
  auto stB = [&](int kt, int h) { dma16(bS[h] + kt * BK, &Bs[kt & 1][h * 4096 + dbase]); };

  f32x4 acc[8][4];
#pragma unroll
  for (int m = 0; m < 8; m++)
#pragma unroll
    for (int n = 0; n < 4; n++) {
      f32x4 z = {0.f, 0.f, 0.f, 0.f};
      acc[m][n] = z;
    }
  int lr = lane & 15, lq = lane >> 4;
  int wr = wv >> 2, wc = wv & 3;           // wave tile: 128 rows x 64 combined cols
  short8 afr[4], bfr[4];

  auto rdB = [&](int s, int kh) {
#pragma unroll
    for (int n = 0; n < 4; n++) {
      int i = wc * 64 + n * 16 + lr;
      bfr[n] = *(const short8*)&Bs[s][i * 64 + (((kh * 4 + lq) ^ (i & 7)) * 8)];
    }
  };
  auto rdA = [&](int s, int kh, int g) {
#pragma unroll
    for (int m = 0; m < 4; m++) {
      int r = wr * 128 + g * 64 + m * 16 + lr;
      afr[m] = *(const short8*)&As[s][r * 64 + (((kh * 4 + lq) ^ (r & 7)) * 8)];
    }
  };
  auto mm = [&](int g) {
    __builtin_amdgcn_s_setprio(1);
#pragma unroll
    for (int m = 0; m < 4; m++)
#pragma unroll
      for (int n = 0; n < 4; n++)
        acc[g * 4 + m][n] = __builtin_amdgcn_mfma_f32_16x16x32_bf16(
            afr[m], bfr[n], acc[g * 4 + m][n], 0, 0, 0);
    __builtin_amdgcn_s_setprio(0);
  };

  // prologue: tile0 complete + tile1 A0,A2 (matches steady state at kt=0.p1)
#pragma unroll
  for (int h = 0; h < 4; h++) { stA(0, h); stB(0, h); }
  stA(1, 0); stA(1, 2);
  WAITVM(2);                               // retire tile0's 8; keep tile1's 2 in flight
  BAR();
  for (int kt = 0; kt < NT1; ++kt) {
    int s = kt & 1;
    // p1 (kh0, g0)
    rdB(s, 0); rdA(s, 0, 0);
    if (kt + 1 < NT1) { stA(kt + 1, 1); stB(kt + 1, 0); }
    BAR(); mm(0); BAR();
    // p2 (kh0, g1) — bfr reused
    rdA(s, 0, 1);
    if (kt + 1 < NT1) { stA(kt + 1, 3); stB(kt + 1, 1); }
    BAR(); mm(1); BAR();
    // p3 (kh1, g0)
    rdB(s, 1); rdA(s, 1, 0);
    if (kt + 1 < NT1) { stB(kt + 1, 2); stB(kt + 1, 3); }
    BAR(); mm(0); BAR();
    // p4 (kh1, g1) — A0/A2 of slot s freed after p3's barrier
    rdA(s, 1, 1);
    if (kt + 2 < NT1) { stA(kt + 2, 0); stA(kt + 2, 2); WAITVM(2); }
    else if (kt + 1 < NT1) { WAITVM(0); }
    BAR(); mm(1); BAR();
  }
  // epilogue: pair g (n even) with u (n odd), silu, store bf16
  int cbase = (blockIdx.y << 7) + wc * 32;  // act col base for this wave
#pragma unroll
  for (int mi = 0; mi < 8; mi++)
#pragma unroll
    for (int np = 0; np < 2; np++)
#pragma unroll
      for (int rg = 0; rg < 4; rg++) {
        float g = acc[mi][2 * np][rg];
        float h = acc[mi][2 * np + 1][rg];
        float a = g * (1.f / (1.f + __expf(-g))) * h;
        int r_loc = wr * 128 + mi * 16 + lq * 4 + rg;
        act[(size_t)(row0l + r_loc) * I_DIM + cbase + np * 16 + lr] = f2bf(a);
      }
}

// ---------------- GEMM2: 128x128 tile, 4 waves, 4-phase fine pipeline, 2 blocks/CU.
// Same 128B-row 8-chunk-XOR layout; 32-row stage chunks (1 dma16/thread).
// out += rowweight * (act @ Wd), fp32 atomics.
__global__ __launch_bounds__(256, 2)
void gemm2_kernel(const u16* __restrict__ act, const u16* __restrict__ wdp,
                  float* __restrict__ out, const int* __restrict__ ctrl, int tile0) {
  __shared__ u16 As[2][128 * 64];
  __shared__ u16 Bs[2][128 * 64];
  int bx = blockIdx.x;
  int tt = tile0 + (bx >> 1);
  if (tt >= ctrl[CI_NTILES]) return;
  int e = ctrl[CI_TILE_E + tt];
  int sub = bx & 1;
  int row0g = (tt << 8) + (sub << 7);      // global padded row base
  int row0l = bx << 7;                     // pass-local act row base
  int col0 = blockIdx.y << 7;              // over C
  const u16* D = wdp + (size_t)e * (I_DIM * C_DIM);
  int tid = threadIdx.x, lane = tid & 63, wv = tid >> 6;
  int lsub = lane >> 3, lchk = lane & 7;
  int co = (lchk ^ lsub) * 8;
  const u16 *aS[4], *bS[4];
#pragma unroll
  for (int q = 0; q < 4; q++) {            // 32-row chunk q: rows q*32 + wv*8 + lsub
    aS[q] = act + (size_t)(row0l + q * 32 + wv * 8 + lsub) * I_DIM + co;
    bS[q] = D + (size_t)(col0 + q * 32 + wv * 8 + lsub) * I_DIM + co;
  }
  int dbase = wv * 512;

  auto stA = [&](int kt, int q) { dma16(aS[q] + kt * BK, &As[kt & 1][q * 2048 + dbase]); };
  auto stB = [&](int kt, int q) { dma16(bS[q] + kt * BK, &Bs[kt & 1][q * 2048 + dbase]); };

  f32x4 acc[4][4];
#pragma unroll
  for (int m = 0; m < 4; m++)
#pragma unroll
    for (int n = 0; n < 4; n++) {
      f32x4 z = {0.f, 0.f, 0.f, 0.f};
      acc[m][n] = z;
    }
  int lr = lane & 15, lq = lane >> 4;
  int wr = wv >> 1, wc = wv & 1;           // wave tile: 64 rows x 64 cols
  short8 afr[2], bfr[4];

  auto rdB = [&](int s, int kh) {
#pragma unroll
    for (int n = 0; n < 4; n++) {
      int i = wc * 64 + n * 16 + lr;
      bfr[n] = *(const short8*)&Bs[s][i * 64 + (((kh * 4 + lq) ^ (i & 7)) * 8)];
    }
  };
  auto rdA = [&](int s, int kh, int mh) {
#pragma unroll
    for (int m = 0; m < 2; m++) {
      int r = wr * 64 + mh * 32 + m * 16 + lr;
      afr[m] = *(const short8*)&As[s][r * 64 + (((kh * 4 + lq) ^ (r & 7)) * 8)];
    }
  };
  auto mm = [&](int mh) {
    __builtin_amdgcn_s_setprio(1);
#pragma unroll
    for (int m = 0; m < 2; m++)
#pragma unroll
      for (int n = 0; n < 4; n++)
        acc[mh * 2 + m][n] = __builtin_amdgcn_mfma_f32_16x16x32_bf16(
            afr[m], bfr[n], acc[mh * 2 + m][n], 0, 0, 0);
    __builtin_amdgcn_s_setprio(0);
  };

#pragma unroll
  for (int q = 0; q < 4; q++) { stA(0, q); stB(0, q); }
  stA(1, 0); stA(1, 2);
  WAITVM(2);
  BAR();
  for (int kt = 0; kt < NT2; ++kt) {
    int s = kt & 1;
    // p1 (kh0, mh0)
    rdB(s, 0); rdA(s, 0, 0);
    if (kt + 1 < NT2) { stA(kt + 1, 1); stB(kt + 1, 0); }
    BAR(); mm(0); BAR();
    // p2 (kh0, mh1)
    rdA(s, 0, 1);
    if (kt + 1 < NT2) { stA(kt + 1, 3); stB(kt + 1, 1); }
    BAR(); mm(1); BAR();
    // p3 (kh1, mh0)
    rdB(s, 1); rdA(s, 1, 0);
    if (kt + 1 < NT2) { stB(kt + 1, 2); stB(kt + 1, 3); }
    BAR(); mm(0); BAR();
    // p4 (kh1, mh1) — A0/A2 of slot s freed after p3
    rdA(s, 1, 1);
    if (kt + 2 < NT2) { stA(kt + 2, 0); stA(kt + 2, 2); WAITVM(2); }
    else if (kt + 1 < NT2) { WAITVM(0); }
    BAR(); mm(1); BAR();
  }
  const int* perm = ctrl + CI_PERM;
  const float* rw = (const float*)(ctrl + CI_RW);
#pragma unroll
  for (int mi = 0; mi < 4; mi++)
#pragma unroll
    for (int rg = 0; rg < 4; rg++) {
      int rgrow = row0g + wr * 64 + mi * 16 + lq * 4 + rg;
      int tokn = perm[rgrow];
      if (tokn < 0) continue;              // padding row
      float w = rw[rgrow];
      float* obase = out + (size_t)tokn * C_DIM + col0 + wc * 64 + lr;
#pragma unroll
      for (int n = 0; n < 4; n++)
        atomicAdd(obase + n * 16, acc[mi][n][rg] * w);
    }
}

extern "C" void kernel_launch(void* const* d_in, const int* in_sizes, int n_in,
                              void* d_out, int out_size, void* d_ws, size_t ws_size,
                              hipStream_t stream) {
  (void)in_sizes; (void)n_in; (void)out_size; (void)ws_size;
  const float* x     = (const float*)d_in[0];
  const float* wgate = (const float*)d_in[1];
  const float* ebias = (const float*)d_in[2];
  const float* wg    = (const float*)d_in[3];
  const float* wu    = (const float*)d_in[4];
  const float* wd    = (const float*)d_in[5];
  const float* swg   = (const float*)d_in[6];
  const float* swu   = (const float*)d_in[7];
  const float* swd   = (const float*)d_in[8];
  float* out = (float*)d_out;
  char* ws = (char*)d_ws;
  int* ctrl = (int*)ws;
  u16* xb  = (u16*)(ws + XB_OFF);
  u16* wgu = (u16*)(ws + WGU_OFF);
  u16* wdp = (u16*)(ws + WDP_OFF);
  u16* act = (u16*)(ws + ACT_OFF);

  hipMemsetAsync(ws, 0, 256, stream);                           // expert counts = 0
  hipMemsetAsync(ws + (size_t)CI_PERM * 4, 0xFF, 53248 * 4, stream);  // perm = -1
  hipMemsetAsync(d_out, 0, (size_t)N_TOK * C_DIM * 4, stream);  // out = 0 (atomic target)
  router_kernel<<<N_TOK / 16, 256, 0, stream>>>(x, wgate, ebias, ctrl, xb);
  tiles_kernel<<<1, 64, 0, stream>>>(ctrl);
  scatter_kernel<<<N_TOK / 256, 256, 0, stream>>>(ctrl);
  convert_kernel<<<17 * 96 + 17 * 24, 256, 0, stream>>>(wg, wu, wd, swg, swu, swd, wgu, wdp);
  for (int p = 0; p < 2; p++) {
    gemm1_kernel<<<dim3(PASS_T, 2 * I_DIM / 256), 512, 0, stream>>>(xb, wgu, act, ctrl, p * PASS_T);
    gemm2_kernel<<<dim3(2 * PASS_T, C_DIM / 128), 256, 0, stream>>>(act, wdp, out, ctrl, p * PASS_T);
  }
}

// Round 4
// 1013.542 us; speedup vs baseline: 1.1111x; 1.1111x over previous
//
#include <hip/hip_runtime.h>

typedef unsigned short u16;
typedef unsigned int u32;
typedef __attribute__((ext_vector_type(4))) float f32x4;
typedef __attribute__((ext_vector_type(8))) short short8;
typedef __attribute__((ext_vector_type(4))) u16 u16x4;
typedef __attribute__((ext_vector_type(8))) u16 u16x8;

#define N_TOK 16384
#define C_DIM 768
#define I_DIM 1536
#define N_EXP 16
#define TM 128
#define BK 64
#define MAXT 400        // worst-case tiles: <=272 routed + 128 shared
#define PASS_T 200      // tiles per pass (two passes)

// ctrl region int offsets (first 1MB of ws)
#define CI_COUNTS 0
#define CI_STARTS 32
#define CI_NTILES 64
#define CI_TILE_E 128        // [400]
#define CI_ESLOT 2048        // [N][2] packed (e<<24)|slot
#define CI_TOKW 36864        // [N][2] float weights
#define CI_PERM 102400       // [51200] padded row -> token (-1 = padding)
#define CI_RW 153600         // [51200] float per-row combine weight

// ws layout (bytes) — total 225,181,696
#define XB_OFF  1048576u             // bf16 x: 16384*768*2 = 25,165,824
#define WGU_OFF 26214400u            // bf16 [17][2I][C] g/u 16-interleaved, XOR-baked: 80,216,064
#define WDP_OFF 106430464u           // bf16 [17][C][I] XOR-baked:    40,108,032
#define ACT_OFF 146538496u           // bf16 act half: 25600*1536*2 = 78,643,200

__device__ __forceinline__ u16 f2bf(float f) {
  u32 x = __float_as_uint(f);
  return (u16)((x + 0x7FFFu + ((x >> 16) & 1u)) >> 16);  // RNE
}
__device__ __forceinline__ float bf2f(u16 h) {
  return __uint_as_float(((u32)h) << 16);
}
__device__ __forceinline__ void dma16(const void* g, void* l) {
  __builtin_amdgcn_global_load_lds(
      (const __attribute__((address_space(1))) unsigned int*)g,
      (__attribute__((address_space(3))) unsigned int*)l, 16, 0, 0);
}

// ---------------- weight convert: fp32 [K][N] -> bf16 [N][K], chunk-XOR swizzle baked.
// wgu: per expert one [3072][768] matrix whose rows interleave g/u at 16-col
// granularity: combined row ng -> gu=(ng>>4)&1, src col ((ng>>5)<<4)|(ng&15).
// A 16-wide MFMA B-fragment is pure g or pure u; fragments n and n+1 of a wave
// cover the SAME output cols (g then u) -> silu pairing is wave-local.
__global__ void convert_kernel(const float* __restrict__ wg, const float* __restrict__ wu,
                               const float* __restrict__ wd, const float* __restrict__ swg,
                               const float* __restrict__ swu, const float* __restrict__ swd,
                               u16* __restrict__ wgu, u16* __restrict__ wdp) {
  int bid = blockIdx.x;
  int tid = threadIdx.x, lane = tid & 63, wv = tid >> 6;
  int lsub = lane >> 3, lchk = lane & 7;
  if (bid < 17 * 96) {                     // combined g/u part: 17 experts x 3072 rows
    int e = bid / 96, nb = bid % 96;
    int ng = nb * 32 + wv * 8 + lsub;      // combined dst row 0..3071
    int gu = (ng >> 4) & 1;
    int scol = ((ng >> 5) << 4) | (ng & 15);
    const float* src = (e < N_EXP) ? ((gu ? wu : wg) + (size_t)e * C_DIM * I_DIM)
                                   : (gu ? swu : swg);
    u16* drow = wgu + ((size_t)e * (2 * I_DIM) + ng) * C_DIM;
    int c = lchk ^ (ng & 7);               // source chunk stored at position lchk
    const float* s0 = src + scol;
    for (int k0 = 0; k0 < C_DIM; k0 += 64) {
      u16x8 o;
#pragma unroll
      for (int j = 0; j < 8; j++) o[j] = f2bf(s0[(size_t)(k0 + c * 8 + j) * I_DIM]);
      *(u16x8*)&drow[k0 + lchk * 8] = o;
    }
  } else {                                 // wd part: [I][C] -> [C][I]
    int b2 = bid - 17 * 96;
    int e = b2 / 24, nb = b2 % 24;
    const float* src = (e < N_EXP) ? (wd + (size_t)e * I_DIM * C_DIM) : swd;
    u16* dst = wdp + (size_t)e * (I_DIM * C_DIM);
    int ng = nb * 32 + wv * 8 + lsub;
    int c = lchk ^ (ng & 7);
    const float* s0 = src + ng;
    u16* drow = dst + (size_t)ng * I_DIM;
    for (int k0 = 0; k0 < I_DIM; k0 += 64) {
      u16x8 o;
#pragma unroll
      for (int j = 0; j < 8; j++) o[j] = f2bf(s0[(size_t)(k0 + c * 8 + j) * C_DIM]);
      *(u16x8*)&drow[k0 + lchk * 8] = o;
    }
  }
}

// ---------------- router: fp32 logits, top-2, weights, counts; also casts x->bf16
__global__ void router_kernel(const float* __restrict__ x, const float* __restrict__ wgate,
                              const float* __restrict__ ebias, int* __restrict__ ctrl,
                              u16* __restrict__ xb) {
  __shared__ float xs[16 * 772];
  __shared__ float wgsT[16 * 772];      // transposed [e][c]
  __shared__ float lg[16 * 16];
  int tid = threadIdx.x;
  int tok0 = blockIdx.x * 16;
  const float4* xsrc = (const float4*)(x + (size_t)tok0 * C_DIM);
  const float4* wsrc = (const float4*)wgate;
#pragma unroll
  for (int j = 0; j < 12; j++) {
    int q = tid + j * 256;              // float4 unit, 0..3071
    float4 v = xsrc[q];
    int tk = q / 192;
    int c4 = q - tk * 192;
    *(float4*)&xs[tk * 772 + c4 * 4] = v;
    u16x4 o; o.x = f2bf(v.x); o.y = f2bf(v.y); o.z = f2bf(v.z); o.w = f2bf(v.w);
    *(u16x4*)(xb + (size_t)tok0 * C_DIM + (size_t)q * 4) = o;   // fused x->bf16 cast
    float4 w = wsrc[q];
    int c = q >> 2, e0 = (q & 3) * 4;
    wgsT[(e0 + 0) * 772 + c] = w.x;
    wgsT[(e0 + 1) * 772 + c] = w.y;
    wgsT[(e0 + 2) * 772 + c] = w.z;
    wgsT[(e0 + 3) * 772 + c] = w.w;
  }
  __syncthreads();
  int tk = tid >> 4, e = tid & 15;
  float acc = ebias[e];
  const float4* xr = (const float4*)&xs[tk * 772];
  const float4* wr = (const float4*)&wgsT[e * 772];
#pragma unroll 4
  for (int c4 = 0; c4 < 192; c4++) {
    float4 xv = xr[c4], wv = wr[c4];
    acc = fmaf(xv.x, wv.x, fmaf(xv.y, wv.y, fmaf(xv.z, wv.z, fmaf(xv.w, wv.w, acc))));
  }
  lg[tk * 16 + e] = acc;
  __syncthreads();
  if (tid < 16) {
    int n = tok0 + tid;
    float l0 = -1e30f, l1 = -1e30f; int i0 = 0, i1 = 0;
#pragma unroll
    for (int j = 0; j < 16; j++) {
      float l = lg[tid * 16 + j];
      if (l > l0) { l1 = l0; i1 = i0; l0 = l; i0 = j; }
      else if (l > l1) { l1 = l; i1 = j; }
    }
    float e1 = __expf(l1 - l0);
    float inv = 1.f / (1.f + e1);
    int s0 = atomicAdd(&ctrl[CI_COUNTS + i0], 1);
    int s1 = atomicAdd(&ctrl[CI_COUNTS + i1], 1);
    ctrl[CI_ESLOT + 2 * n]     = (i0 << 24) | s0;
    ctrl[CI_ESLOT + 2 * n + 1] = (i1 << 24) | s1;
    float* tw = (float*)(ctrl + CI_TOKW);
    tw[2 * n] = inv; tw[2 * n + 1] = e1 * inv;
  }
}

// ---------------- segment starts (padded to 128) + tile->expert map; shared = expert 16
__global__ void tiles_kernel(int* __restrict__ ctrl) {
  if (threadIdx.x != 0) return;
  int cnt[17];
#pragma unroll
  for (int e = 0; e < 16; e++) cnt[e] = ctrl[CI_COUNTS + e];
  cnt[16] = N_TOK;
  ctrl[CI_COUNTS + 16] = N_TOK;
  int cur = 0, T = 0;
  for (int e = 0; e <= 16; e++) {
    ctrl[CI_STARTS + e] = cur;
    int nt = (cnt[e] + TM - 1) >> 7;
    for (int i = 0; i < nt; i++) ctrl[CI_TILE_E + T++] = e;
    cur += nt << 7;
  }
  ctrl[CI_NTILES] = T;
}

// ---------------- scatter: fill perm[row]->token and per-row combine weight
__global__ void scatter_kernel(int* __restrict__ ctrl) {
  int n = blockIdx.x * 256 + threadIdx.x;
  const float* tw = (const float*)(ctrl + CI_TOKW);
  float* rw = (float*)(ctrl + CI_RW);
#pragma unroll
  for (int k = 0; k < 2; k++) {
    int es = ctrl[CI_ESLOT + 2 * n + k];
    int e = es >> 24;
    int slot = es & 0xFFFFFF;
    int row = ctrl[CI_STARTS + e] + slot;
    ctrl[CI_PERM + row] = n;
    rw[row] = tw[2 * n + k];
  }
  int srow = ctrl[CI_STARTS + 16] + n;     // shared expert row
  ctrl[CI_PERM + srow] = n;
  rw[srow] = 1.0f;
}

// ---------------- GEMM1: round-0 2-barrier structure, 128x128-COMBINED tile.
// Single B buffer (g/u interleaved wgu) + single acc[4][4] (64 acc regs vs 128)
// -> ~146 regs/thread, LDS 32KB -> 3 blocks/CU resident (was reg-capped at 2).
// act = silu(x@Wg) * (x@Wu); pairing is in-wave (acc n even=g, odd=u).
__global__ __launch_bounds__(256, 3)
void gemm1_kernel(const u16* __restrict__ xb, const u16* __restrict__ wgu,
                  u16* __restrict__ act, const int* __restrict__ ctrl, int tile0) {
  __shared__ u16 Al[TM * BK];
  __shared__ u16 Bl[TM * BK];
  int t = tile0 + blockIdx.x;
  if (t >= ctrl[CI_NTILES]) return;
  int e = ctrl[CI_TILE_E + t];
  int row0 = t << 7;                       // global padded row base
  int row0l = blockIdx.x << 7;             // pass-local row base (act index)
  int col0c = blockIdx.y << 7;             // combined col base (0..3071 step 128)
  int seg_start = ctrl[CI_STARTS + e];
  bool sh = (e == N_EXP);
  const u16* W = wgu + (size_t)e * (2 * I_DIM) * C_DIM;
  int row_lim = sh ? 0x7fffffff : (seg_start + ctrl[CI_COUNTS + e]);
  const int* perm = ctrl + CI_PERM;
  int tid = threadIdx.x;
  int lane = tid & 63, wv = tid >> 6;
  int lsub = lane >> 3;                    // row within 8-row DMA group
  int lchk = lane & 7;                     // chunk position in LDS
  int co = (lchk ^ lsub) * 8;              // A per-lane swizzled source chunk (elems)
  const u16* aptr[4];
#pragma unroll
  for (int j = 0; j < 4; j++) {
    int r = row0 + wv * 32 + j * 8 + lsub;
    int tok = sh ? (r - seg_start) : ((r < row_lim) ? perm[r] : 0);
    aptr[j] = xb + (size_t)tok * C_DIM + co;
  }
  size_t boff = (size_t)(col0c + wv * 32 + lsub) * C_DIM + lchk * 8;  // swizzle baked in wgu
  int ldst = wv * 2048;                    // u16 elems; + j*512

  f32x4 acc[4][4];
#pragma unroll
  for (int m = 0; m < 4; m++)
#pragma unroll
    for (int n = 0; n < 4; n++) {
      f32x4 z = {0.f, 0.f, 0.f, 0.f};
      acc[m][n] = z;
    }
  int lr = lane & 15, lq = lane >> 4;
  int rh = (wv & 1) * 64, chh = (wv >> 1) * 64;

  for (int kk = 0; kk < C_DIM; kk += BK) {
#pragma unroll
    for (int j = 0; j < 4; j++) {
      dma16(aptr[j] + kk,                    Al + ldst + j * 512);
      dma16(W + boff + j * (8 * C_DIM) + kk, Bl + ldst + j * 512);
    }
    __syncthreads();
#pragma unroll
    for (int s = 0; s < 2; s++) {
      int cidx = s * 4 + lq;
      short8 af[4], bf_[4];
#pragma unroll
      for (int m = 0; m < 4; m++) {
        int r = rh + m * 16 + lr;
        af[m] = *(const short8*)&Al[r * 64 + ((cidx ^ (r & 7)) * 8)];
      }
#pragma unroll
      for (int n = 0; n < 4; n++) {
        int i = chh + n * 16 + lr;
        bf_[n] = *(const short8*)&Bl[i * 64 + ((cidx ^ (i & 7)) * 8)];
      }
#pragma unroll
      for (int m = 0; m < 4; m++)
#pragma unroll
        for (int n = 0; n < 4; n++)
          acc[m][n] = __builtin_amdgcn_mfma_f32_16x16x32_bf16(af[m], bf_[n], acc[m][n], 0, 0, 0);
    }
    __syncthreads();
  }
  // epilogue: pair g (n even) with u (n odd); combined col i -> out col (i>>5)*16+(i&15)
  int cbase = (blockIdx.y << 6) + (chh >> 1);  // act col base for this wave
#pragma unroll
  for (int m = 0; m < 4; m++)
#pragma unroll
    for (int np = 0; np < 2; np++)
#pragma unroll
      for (int rg = 0; rg < 4; rg++) {
        float g = acc[m][2 * np][rg];
        float h = acc[m][2 * np + 1][rg];
        float a = g * (1.f / (1.f + __expf(-g))) * h;
        int r_loc = rh + m * 16 + lq * 4 + rg;
        act[(size_t)(row0l + r_loc) * I_DIM + cbase + np * 16 + lr] = f2bf(a);
      }
}

// ---------------- GEMM2: out += rowweight * (act @ Wd), fp32 atomics (round-0 verbatim)
__global__ __launch_bounds__(256, 3)
void gemm2_kernel(const u16* __restrict__ act, const u16* __restrict__ wdp,
                  float* __restrict__ out, const int* __restrict__ ctrl, int tile0) {
  __shared__ u16 Al[TM * BK];
  __shared__ u16 Bl[TM * BK];
  int t = tile0 + blockIdx.x;
  if (t >= ctrl[CI_NTILES]) return;
  int e = ctrl[CI_TILE_E + t];
  int row0 = t << 7;
  int row0l = blockIdx.x << 7;
  int col0 = blockIdx.y * TM;             // over C
  const u16* D = wdp + (size_t)e * (I_DIM * C_DIM);
  int tid = threadIdx.x;
  int lane = tid & 63, wv = tid >> 6;
  int lsub = lane >> 3, lchk = lane & 7;
  int co = (lchk ^ lsub) * 8;
  const u16* abase = act + (size_t)(row0l + wv * 32 + lsub) * I_DIM + co;
  size_t boff = (size_t)(col0 + wv * 32 + lsub) * I_DIM + lchk * 8;
  int ldst = wv * 2048;

  f32x4 acc[4][4];
#pragma unroll
  for (int m = 0; m < 4; m++)
#pragma unroll
    for (int n = 0; n < 4; n++) {
      f32x4 z = {0.f, 0.f, 0.f, 0.f};
      acc[m][n] = z;
    }
  int lr = lane & 15, lq = lane >> 4;
  int rh = (wv & 1) * 64, chh = (wv >> 1) * 64;

  for (int kk = 0; kk < I_DIM; kk += BK) {
#pragma unroll
    for (int j = 0; j < 4; j++) {
      dma16(abase + (size_t)j * 8 * I_DIM + kk, Al + ldst + j * 512);
      dma16(D + boff + j * (8 * I_DIM) + kk,    Bl + ldst + j * 512);
    }
    __syncthreads();
#pragma unroll
    for (int s = 0; s < 2; s++) {
      int cidx = s * 4 + lq;
      short8 af[4], bf_[4];
#pragma unroll
      for (int m = 0; m < 4; m++) {
        int r = rh + m * 16 + lr;
        af[m] = *(const short8*)&Al[r * 64 + ((cidx ^ (r & 7)) * 8)];
      }
#pragma unroll
      for (int n = 0; n < 4; n++) {
        int i = chh + n * 16 + lr;
        bf_[n] = *(const short8*)&Bl[i * 64 + ((cidx ^ (i & 7)) * 8)];
      }
#pragma unroll
      for (int m = 0; m < 4; m++)
#pragma unroll
        for (int n = 0; n < 4; n++)
          acc[m][n] = __builtin_amdgcn_mfma_f32_16x16x32_bf16(af[m], bf_[n], acc[m][n], 0, 0, 0);
    }
    __syncthreads();
  }
  const int* perm = ctrl + CI_PERM;
  const float* rw = (const float*)(ctrl + CI_RW);
#pragma unroll
  for (int m = 0; m < 4; m++)
#pragma unroll
    for (int rg = 0; rg < 4; rg++) {
      int rgrow = row0 + rh + m * 16 + lq * 4 + rg;
      int tokn = perm[rgrow];
      if (tokn < 0) continue;              // padding row
      float w = rw[rgrow];
      float* obase = out + (size_t)tokn * C_DIM + col0 + chh + lr;
#pragma unroll
      for (int n = 0; n < 4; n++)
        atomicAdd(obase + n * 16, acc[m][n][rg] * w);
    }
}

extern "C" void kernel_launch(void* const* d_in, const int* in_sizes, int n_in,
                              void* d_out, int out_size, void* d_ws, size_t ws_size,
                              hipStream_t stream) {
  (void)in_sizes; (void)n_in; (void)out_size; (void)ws_size;
  const float* x     = (const float*)d_in[0];
  const float* wgate = (const float*)d_in[1];
  const float* ebias = (const float*)d_in[2];
  const float* wg    = (const float*)d_in[3];
  const float* wu    = (const float*)d_in[4];
  const float* wd    = (const float*)d_in[5];
  const float* swg   = (const float*)d_in[6];
  const float* swu   = (const float*)d_in[7];
  const float* swd   = (const float*)d_in[8];
  float* out = (float*)d_out;
  char* ws = (char*)d_ws;
  int* ctrl = (int*)ws;
  u16* xb  = (u16*)(ws + XB_OFF);
  u16* wgu = (u16*)(ws + WGU_OFF);
  u16* wdp = (u16*)(ws + WDP_OFF);
  u16* act = (u16*)(ws + ACT_OFF);

  hipMemsetAsync(ws, 0, 256, stream);                           // expert counts = 0
  hipMemsetAsync(ws + (size_t)CI_PERM * 4, 0xFF, 51200 * 4, stream);  // perm = -1
  hipMemsetAsync(d_out, 0, (size_t)N_TOK * C_DIM * 4, stream);  // out = 0 (atomic target)
  router_kernel<<<N_TOK / 16, 256, 0, stream>>>(x, wgate, ebias, ctrl, xb);
  tiles_kernel<<<1, 64, 0, stream>>>(ctrl);
  scatter_kernel<<<N_TOK / 256, 256, 0, stream>>>(ctrl);
  convert_kernel<<<17 * 96 + 17 * 24, 256, 0, stream>>>(wg, wu, wd, swg, swu, swd, wgu, wdp);
  for (int p = 0; p < 2; p++) {
    gemm1_kernel<<<dim3(PASS_T, 2 * I_DIM / TM), 256, 0, stream>>>(xb, wgu, act, ctrl, p * PASS_T);
    gemm2_kernel<<<dim3(PASS_T, C_DIM / TM), 256, 0, stream>>>(act, wdp, out, ctrl, p * PASS_T);
  }
}

// Round 5
// 955.540 us; speedup vs baseline: 1.1785x; 1.0607x over previous
//
#include <hip/hip_runtime.h>

typedef unsigned short u16;
typedef unsigned int u32;
typedef __attribute__((ext_vector_type(4))) float f32x4;
typedef __attribute__((ext_vector_type(8))) short short8;
typedef __attribute__((ext_vector_type(4))) u16 u16x4;
typedef __attribute__((ext_vector_type(8))) u16 u16x8;

#define N_TOK 16384
#define C_DIM 768
#define I_DIM 1536
#define N_EXP 16
#define TM 128
#define BK 64
#define MAXT 400        // worst-case tiles: <=272 routed + 128 shared
#define PASS_T 200      // tiles per pass (two passes)

// ctrl region int offsets (first 1MB of ws)
#define CI_COUNTS 0
#define CI_STARTS 32
#define CI_NTILES 64
#define CI_TILE_E 128        // [400]
#define CI_ESLOT 2048        // [N][2] packed (e<<24)|slot
#define CI_TOKW 36864        // [N][2] float weights
#define CI_PERM 102400       // [51200] padded row -> token (-1 = padding)
#define CI_RW 153600         // [51200] float per-row combine weight

// ws layout (bytes) — total 225,181,696
#define XB_OFF  1048576u             // bf16 x: 16384*768*2 = 25,165,824
#define WGU_OFF 26214400u            // bf16 [17][2][I][C] swizzled: 80,216,064
#define WDP_OFF 106430464u           // bf16 [17][C][I] swizzled:    40,108,032
#define ACT_OFF 146538496u           // bf16 act half: 25600*1536*2 = 78,643,200

__device__ __forceinline__ u16 f2bf(float f) {
  u32 x = __float_as_uint(f);
  return (u16)((x + 0x7FFFu + ((x >> 16) & 1u)) >> 16);  // RNE
}
__device__ __forceinline__ float bf2f(u16 h) {
  return __uint_as_float(((u32)h) << 16);
}
__device__ __forceinline__ void dma16(const void* g, void* l) {
  __builtin_amdgcn_global_load_lds(
      (const __attribute__((address_space(1))) unsigned int*)g,
      (__attribute__((address_space(3))) unsigned int*)l, 16, 0, 0);
}

// ---------------- weight convert: fp32 [K][N] -> bf16 [N][K], chunk-XOR swizzle baked.
// Transpose-through-LDS: reads are float4 along SOURCE rows (fully coalesced),
// writes are contiguous 128B dst rows (fully coalesced). Output bit-identical
// to the old gather version: dst[ng*K + k0 + lchk*8 + j] = src[(k0+c*8+j)*N + ng],
// c = lchk ^ (ng&7).
__global__ void convert_kernel(const float* __restrict__ wg, const float* __restrict__ wu,
                               const float* __restrict__ wd, const float* __restrict__ swg,
                               const float* __restrict__ swu, const float* __restrict__ swd,
                               u16* __restrict__ wgu, u16* __restrict__ wdp) {
  __shared__ u16 lt[64][66];               // [k][ng_local], +2 pad
  int bid = blockIdx.x, tid = threadIdx.x;
  const float* src; u16* dst; int K, N, ng0;
  if (bid < 34 * 24) {                     // g/u part: m = 2e+gu, src [C][I]
    int m = bid / 24, nb = bid % 24;
    int e = m >> 1, gu = m & 1;
    src = (e < N_EXP) ? ((gu ? wu : wg) + (size_t)e * C_DIM * I_DIM) : (gu ? swu : swg);
    dst = wgu + (size_t)m * (C_DIM * I_DIM);
    K = C_DIM; N = I_DIM; ng0 = nb * 64;
  } else {                                 // wd part: src [I][C]
    int b2 = bid - 34 * 24;
    int e = b2 / 12, nb = b2 % 12;
    src = (e < N_EXP) ? (wd + (size_t)e * I_DIM * C_DIM) : swd;
    dst = wdp + (size_t)e * (I_DIM * C_DIM);
    K = I_DIM; N = C_DIM; ng0 = nb * 64;
  }
  for (int k0 = 0; k0 < K; k0 += 64) {
    // read [64 k][64 ng] fp32 tile, 16 float4 per source row
#pragma unroll
    for (int it = 0; it < 4; it++) {
      int fidx = it * 256 + tid;           // 0..1023
      int k = fidx >> 4, c4 = (fidx & 15) * 4;
      float4 v = *(const float4*)&src[(size_t)(k0 + k) * N + ng0 + c4];
      lt[k][c4 + 0] = f2bf(v.x);
      lt[k][c4 + 1] = f2bf(v.y);
      lt[k][c4 + 2] = f2bf(v.z);
      lt[k][c4 + 3] = f2bf(v.w);
    }
    __syncthreads();
    // write [64 ng][64 k] bf16 rows, chunk-XOR baked, 16B stores (8 thr = 128B row)
#pragma unroll
    for (int it = 0; it < 2; it++) {
      int slot = it * 256 + tid;           // 0..511
      int ngl = slot >> 3, lchk = slot & 7;
      int ng = ng0 + ngl;
      int c = lchk ^ (ng & 7);
      u16x8 o;
#pragma unroll
      for (int j = 0; j < 8; j++) o[j] = lt[c * 8 + j][ngl];
      *(u16x8*)&dst[(size_t)ng * K + k0 + lchk * 8] = o;
    }
    __syncthreads();
  }
}

// ---------------- router: fp32 logits, top-2, weights, counts; also casts x->bf16
__global__ void router_kernel(const float* __restrict__ x, const float* __restrict__ wgate,
                              const float* __restrict__ ebias, int* __restrict__ ctrl,
                              u16* __restrict__ xb) {
  __shared__ float xs[16 * 772];
  __shared__ float wgsT[16 * 772];      // transposed [e][c]
  __shared__ float lg[16 * 16];
  int tid = threadIdx.x;
  int tok0 = blockIdx.x * 16;
  const float4* xsrc = (const float4*)(x + (size_t)tok0 * C_DIM);
  const float4* wsrc = (const float4*)wgate;
#pragma unroll
  for (int j = 0; j < 12; j++) {
    int q = tid + j * 256;              // float4 unit, 0..3071
    float4 v = xsrc[q];
    int tk = q / 192;
    int c4 = q - tk * 192;
    *(float4*)&xs[tk * 772 + c4 * 4] = v;
    u16x4 o; o.x = f2bf(v.x); o.y = f2bf(v.y); o.z = f2bf(v.z); o.w = f2bf(v.w);
    *(u16x4*)(xb + (size_t)tok0 * C_DIM + (size_t)q * 4) = o;   // fused x->bf16 cast
    float4 w = wsrc[q];
    int c = q >> 2, e0 = (q & 3) * 4;
    wgsT[(e0 + 0) * 772 + c] = w.x;
    wgsT[(e0 + 1) * 772 + c] = w.y;
    wgsT[(e0 + 2) * 772 + c] = w.z;
    wgsT[(e0 + 3) * 772 + c] = w.w;
  }
  __syncthreads();
  int tk = tid >> 4, e = tid & 15;
  float acc = ebias[e];
  const float4* xr = (const float4*)&xs[tk * 772];
  const float4* wr = (const float4*)&wgsT[e * 772];
#pragma unroll 4
  for (int c4 = 0; c4 < 192; c4++) {
    float4 xv = xr[c4], wv = wr[c4];
    acc = fmaf(xv.x, wv.x, fmaf(xv.y, wv.y, fmaf(xv.z, wv.z, fmaf(xv.w, wv.w, acc))));
  }
  lg[tk * 16 + e] = acc;
  __syncthreads();
  if (tid < 16) {
    int n = tok0 + tid;
    float l0 = -1e30f, l1 = -1e30f; int i0 = 0, i1 = 0;
#pragma unroll
    for (int j = 0; j < 16; j++) {
      float l = lg[tid * 16 + j];
      if (l > l0) { l1 = l0; i1 = i0; l0 = l; i0 = j; }
      else if (l > l1) { l1 = l; i1 = j; }
    }
    float e1 = __expf(l1 - l0);
    float inv = 1.f / (1.f + e1);
    int s0 = atomicAdd(&ctrl[CI_COUNTS + i0], 1);
    int s1 = atomicAdd(&ctrl[CI_COUNTS + i1], 1);
    ctrl[CI_ESLOT + 2 * n]     = (i0 << 24) | s0;
    ctrl[CI_ESLOT + 2 * n + 1] = (i1 << 24) | s1;
    float* tw = (float*)(ctrl + CI_TOKW);
    tw[2 * n] = inv; tw[2 * n + 1] = e1 * inv;
  }
}

// ---------------- segment starts (padded to 128) + tile->expert map; shared = expert 16
__global__ void tiles_kernel(int* __restrict__ ctrl) {
  if (threadIdx.x != 0) return;
  int cnt[17];
#pragma unroll
  for (int e = 0; e < 16; e++) cnt[e] = ctrl[CI_COUNTS + e];
  cnt[16] = N_TOK;
  ctrl[CI_COUNTS + 16] = N_TOK;
  int cur = 0, T = 0;
  for (int e = 0; e <= 16; e++) {
    ctrl[CI_STARTS + e] = cur;
    int nt = (cnt[e] + TM - 1) >> 7;
    for (int i = 0; i < nt; i++) ctrl[CI_TILE_E + T++] = e;
    cur += nt << 7;
  }
  ctrl[CI_NTILES] = T;
}

// ---------------- scatter: fill perm[row]->token and per-row combine weight
__global__ void scatter_kernel(int* __restrict__ ctrl) {
  int n = blockIdx.x * 256 + threadIdx.x;
  const float* tw = (const float*)(ctrl + CI_TOKW);
  float* rw = (float*)(ctrl + CI_RW);
#pragma unroll
  for (int k = 0; k < 2; k++) {
    int es = ctrl[CI_ESLOT + 2 * n + k];
    int e = es >> 24;
    int slot = es & 0xFFFFFF;
    int row = ctrl[CI_STARTS + e] + slot;
    ctrl[CI_PERM + row] = n;
    rw[row] = tw[2 * n + k];
  }
  int srow = ctrl[CI_STARTS + 16] + n;     // shared expert row
  ctrl[CI_PERM + srow] = n;
  rw[srow] = 1.0f;
}

// ---------------- GEMM1: act = silu(x@Wg) * (x@Wu), gathered rows, DMA staging
__global__ __launch_bounds__(256, 2)
void gemm1_kernel(const u16* __restrict__ xb, const u16* __restrict__ wgu,
                  u16* __restrict__ act, const int* __restrict__ ctrl, int tile0) {
  __shared__ u16 Al[TM * BK];
  __shared__ u16 Bg[TM * BK];
  __shared__ u16 Bu[TM * BK];
  int t = tile0 + blockIdx.x;
  if (t >= ctrl[CI_NTILES]) return;
  int e = ctrl[CI_TILE_E + t];
  int row0 = t << 7;                       // global padded row base
  int row0l = blockIdx.x << 7;             // pass-local row base (act index)
  int col0 = blockIdx.y * TM;
  int seg_start = ctrl[CI_STARTS + e];
  bool sh = (e == N_EXP);
  const u16* G = wgu + (size_t)(2 * e) * (C_DIM * I_DIM);
  const u16* U = G + C_DIM * I_DIM;
  int row_lim = sh ? 0x7fffffff : (seg_start + ctrl[CI_COUNTS + e]);
  const int* perm = ctrl + CI_PERM;
  int tid = threadIdx.x;
  int lane = tid & 63, wv = tid >> 6;
  int lsub = lane >> 3;                    // row within 8-row DMA group
  int lchk = lane & 7;                     // chunk position in LDS
  int co = (lchk ^ lsub) * 8;              // A per-lane swizzled source chunk (elems)
  const u16* aptr[4];
#pragma unroll
  for (int j = 0; j < 4; j++) {
    int r = row0 + wv * 32 + j * 8 + lsub;
    int tok = sh ? (r - seg_start) : ((r < row_lim) ? perm[r] : 0);
    aptr[j] = xb + (size_t)tok * C_DIM + co;
  }
  size_t boff = (size_t)(col0 + wv * 32 + lsub) * C_DIM + lchk * 8;  // swizzle baked in wgu
  int ldst = wv * 2048;                    // u16 elems; + j*512

  f32x4 accg[4][4], accu[4][4];
#pragma unroll
  for (int m = 0; m < 4; m++)
#pragma unroll
    for (int n = 0; n < 4; n++) {
      f32x4 z = {0.f, 0.f, 0.f, 0.f};
      accg[m][n] = z; accu[m][n] = z;
    }
  int lr = lane & 15, lq = lane >> 4;
  int rh = (wv & 1) * 64, chh = (wv >> 1) * 64;

  for (int kk = 0; kk < C_DIM; kk += BK) {
#pragma unroll
    for (int j = 0; j < 4; j++) {
      dma16(aptr[j] + kk,                    Al + ldst + j * 512);
      dma16(G + boff + j * (8 * C_DIM) + kk, Bg + ldst + j * 512);
      dma16(U + boff + j * (8 * C_DIM) + kk, Bu + ldst + j * 512);
    }
    __syncthreads();
#pragma unroll
    for (int s = 0; s < 2; s++) {
      int cidx = s * 4 + lq;
      short8 af[4], bg_[4], bu_[4];
#pragma unroll
      for (int m = 0; m < 4; m++) {
        int r = rh + m * 16 + lr;
        af[m] = *(const short8*)&Al[r * 64 + ((cidx ^ (r & 7)) * 8)];
      }
#pragma unroll
      for (int n = 0; n < 4; n++) {
        int i = chh + n * 16 + lr;
        int off = i * 64 + ((cidx ^ (i & 7)) * 8);
        bg_[n] = *(const short8*)&Bg[off];
        bu_[n] = *(const short8*)&Bu[off];
      }
#pragma unroll
      for (int m = 0; m < 4; m++)
#pragma unroll
        for (int n = 0; n < 4; n++) {
          accg[m][n] = __builtin_amdgcn_mfma_f32_16x16x32_bf16(af[m], bg_[n], accg[m][n], 0, 0, 0);
          accu[m][n] = __builtin_amdgcn_mfma_f32_16x16x32_bf16(af[m], bu_[n], accu[m][n], 0, 0, 0);
        }
    }
    __syncthreads();
  }
#pragma unroll
  for (int m = 0; m < 4; m++)
#pragma unroll
    for (int n = 0; n < 4; n++)
#pragma unroll
      for (int rg = 0; rg < 4; rg++) {
        float g = accg[m][n][rg];
        float h = accu[m][n][rg];
        float a = g * (1.f / (1.f + __expf(-g))) * h;
        int r_loc = rh + m * 16 + lq * 4 + rg;
        int cl = col0 + chh + n * 16 + lr;
        act[(size_t)(row0l + r_loc) * I_DIM + cl] = f2bf(a);
      }
}

// ---------------- GEMM2: out += rowweight * (act @ Wd), fp32 atomics, no y buffer
__global__ __launch_bounds__(256, 3)
void gemm2_kernel(const u16* __restrict__ act, const u16* __restrict__ wdp,
                  float* __restrict__ out, const int* __restrict__ ctrl, int tile0) {
  __shared__ u16 Al[TM * BK];
  __shared__ u16 Bl[TM * BK];
  int t = tile0 + blockIdx.x;
  if (t >= ctrl[CI_NTILES]) return;
  int e = ctrl[CI_TILE_E + t];
  int row0 = t << 7;
  int row0l = blockIdx.x << 7;
  int col0 = blockIdx.y * TM;             // over C
  const u16* D = wdp + (size_t)e * (I_DIM * C_DIM);
  int tid = threadIdx.x;
  int lane = tid & 63, wv = tid >> 6;
  int lsub = lane >> 3, lchk = lane & 7;
  int co = (lchk ^ lsub) * 8;
  const u16* abase = act + (size_t)(row0l + wv * 32 + lsub) * I_DIM + co;
  size_t boff = (size_t)(col0 + wv * 32 + lsub) * I_DIM + lchk * 8;
  int ldst = wv * 2048;

  f32x4 acc[4][4];
#pragma unroll
  for (int m = 0; m < 4; m++)
#pragma unroll
    for (int n = 0; n < 4; n++) {
      f32x4 z = {0.f, 0.f, 0.f, 0.f};
      acc[m][n] = z;
    }
  int lr = lane & 15, lq = lane >> 4;
  int rh = (wv & 1) * 64, chh = (wv >> 1) * 64;

  for (int kk = 0; kk < I_DIM; kk += BK) {
#pragma unroll
    for (int j = 0; j < 4; j++) {
      dma16(abase + (size_t)j * 8 * I_DIM + kk, Al + ldst + j * 512);
      dma16(D + boff + j * (8 * I_DIM) + kk,    Bl + ldst + j * 512);
    }
    __syncthreads();
#pragma unroll
    for (int s = 0; s < 2; s++) {
      int cidx = s * 4 + lq;
      short8 af[4], bf_[4];
#pragma unroll
      for (int m = 0; m < 4; m++) {
        int r = rh + m * 16 + lr;
        af[m] = *(const short8*)&Al[r * 64 + ((cidx ^ (r & 7)) * 8)];
      }
#pragma unroll
      for (int n = 0; n < 4; n++) {
        int i = chh + n * 16 + lr;
        bf_[n] = *(const short8*)&Bl[i * 64 + ((cidx ^ (i & 7)) * 8)];
      }
#pragma unroll
      for (int m = 0; m < 4; m++)
#pragma unroll
        for (int n = 0; n < 4; n++)
          acc[m][n] = __builtin_amdgcn_mfma_f32_16x16x32_bf16(af[m], bf_[n], acc[m][n], 0, 0, 0);
    }
    __syncthreads();
  }
  const int* perm = ctrl + CI_PERM;
  const float* rw = (const float*)(ctrl + CI_RW);
#pragma unroll
  for (int m = 0; m < 4; m++)
#pragma unroll
    for (int rg = 0; rg < 4; rg++) {
      int rgrow = row0 + rh + m * 16 + lq * 4 + rg;
      int tokn = perm[rgrow];
      if (tokn < 0) continue;              // padding row
      float w = rw[rgrow];
      float* obase = out + (size_t)tokn * C_DIM + col0 + chh + lr;
#pragma unroll
      for (int n = 0; n < 4; n++)
        atomicAdd(obase + n * 16, acc[m][n][rg] * w);
    }
}

extern "C" void kernel_launch(void* const* d_in, const int* in_sizes, int n_in,
                              void* d_out, int out_size, void* d_ws, size_t ws_size,
                              hipStream_t stream) {
  (void)in_sizes; (void)n_in; (void)out_size; (void)ws_size;
  const float* x     = (const float*)d_in[0];
  const float* wgate = (const float*)d_in[1];
  const float* ebias = (const float*)d_in[2];
  const float* wg    = (const float*)d_in[3];
  const float* wu    = (const float*)d_in[4];
  const float* wd    = (const float*)d_in[5];
  const float* swg   = (const float*)d_in[6];
  const float* swu   = (const float*)d_in[7];
  const float* swd   = (const float*)d_in[8];
  float* out = (float*)d_out;
  char* ws = (char*)d_ws;
  int* ctrl = (int*)ws;
  u16* xb  = (u16*)(ws + XB_OFF);
  u16* wgu = (u16*)(ws + WGU_OFF);
  u16* wdp = (u16*)(ws + WDP_OFF);
  u16* act = (u16*)(ws + ACT_OFF);

  hipMemsetAsync(ws, 0, 256, stream);                           // expert counts = 0
  hipMemsetAsync(ws + (size_t)CI_PERM * 4, 0xFF, 51200 * 4, stream);  // perm = -1
  hipMemsetAsync(d_out, 0, (size_t)N_TOK * C_DIM * 4, stream);  // out = 0 (atomic target)
  router_kernel<<<N_TOK / 16, 256, 0, stream>>>(x, wgate, ebias, ctrl, xb);
  tiles_kernel<<<1, 64, 0, stream>>>(ctrl);
  scatter_kernel<<<N_TOK / 256, 256, 0, stream>>>(ctrl);
  convert_kernel<<<34 * 24 + 17 * 12, 256, 0, stream>>>(wg, wu, wd, swg, swu, swd, wgu, wdp);
  for (int p = 0; p < 2; p++) {
    gemm1_kernel<<<dim3(PASS_T, I_DIM / TM), 256, 0, stream>>>(xb, wgu, act, ctrl, p * PASS_T);
    gemm2_kernel<<<dim3(PASS_T, C_DIM / TM), 256, 0, stream>>>(act, wdp, out, ctrl, p * PASS_T);
  }
}